// Round 2
// baseline (19524.557 us; speedup 1.0000x reference)
//
#include <hip/hip_runtime.h>
#include <cstdint>
#include <cstddef>

// Problem constants
#define kSEQ 100
#define kB   200
#define kNP  512
#define kNG  4096
#define kMP  256     // padded M for recurrent/encoder GEMMs
#define KSPLIT 8

typedef __bf16 bf16_t;
typedef bf16_t bf16x8 __attribute__((ext_vector_type(8)));
typedef float  f32x4  __attribute__((ext_vector_type(4)));

__device__ __forceinline__ unsigned short f2bf(float f) {
    unsigned int u = __builtin_bit_cast(unsigned int, f);
    unsigned int r = (u + 0x7FFFu + ((u >> 16) & 1u)) >> 16;
    return (unsigned short)r;
}
__device__ __forceinline__ float bf2f(unsigned short b) {
    unsigned int u = ((unsigned int)b) << 16;
    return __builtin_bit_cast(float, u);
}

__device__ __forceinline__ void gld_lds16(const void* g, void* l) {
    auto gp = (const __attribute__((address_space(1))) unsigned int*)(g);
    auto lp = (__attribute__((address_space(3))) unsigned int*)(l);
    __builtin_amdgcn_global_load_lds(gp, lp, 16, 0, 0);
}

// Stage a 128-row x 64-col bf16 chunk into LDS (linear layout, content
// swizzled: LDS 16B-chunk c of row r holds global chunk c^(r&7)).
// 1024 slots of 16B; wave w covers slots [w*256, w*256+255] in 4 issues.
__device__ __forceinline__ void stage16(const unsigned short* gbase, int ldElems,
                                        int row0, int k0, unsigned short* lds,
                                        int w, int lane) {
#pragma unroll
    for (int j = 0; j < 4; ++j) {
        int s   = w * 256 + j * 64 + lane;
        int row = s >> 3;
        int c16 = s & 7;
        int csw = c16 ^ (row & 7);
        const char* src = (const char*)(gbase + (size_t)(row0 + row) * ldElems + k0) + csw * 16;
        char* dst = (char*)lds + (size_t)(w * 256 + j * 64) * 16;   // wave-uniform
        gld_lds16(src, dst);
    }
}

// ---------------------------------------------------------------------------
// Split fp32 -> (hi, lo) bf16 pair.
// ---------------------------------------------------------------------------
__global__ __launch_bounds__(256)
void k_split(const float* __restrict__ src, unsigned short* __restrict__ hi,
             unsigned short* __restrict__ lo, int n4) {
    int i = blockIdx.x * 256 + threadIdx.x;
    if (i >= n4) return;
    float4 v = ((const float4*)src)[i];
    ushort4 h, l;
    h.x = f2bf(v.x); l.x = f2bf(v.x - bf2f(h.x));
    h.y = f2bf(v.y); l.y = f2bf(v.y - bf2f(h.y));
    h.z = f2bf(v.z); l.z = f2bf(v.z - bf2f(h.z));
    h.w = f2bf(v.w); l.w = f2bf(v.w - bf2f(h.w));
    ((ushort4*)hi)[i] = h;
    ((ushort4*)lo)[i] = l;
}

// ---------------------------------------------------------------------------
// Fused split-precision GEMM step + split-K semaphore epilogue.
// Grid: 512 WGs, 256 threads (4 waves of 64x64 frags, 128x128 tile).
// Block decode (XCD-colocating): all 16 WGs (2m x 8k) of an n-tile on 1 XCD.
// mode 0: encoder (no vx/relu/g); mode 1: scan step.
// ---------------------------------------------------------------------------
__global__ __launch_bounds__(256, 2)
void k_step(const unsigned short* __restrict__ Ahi, const unsigned short* __restrict__ Alo, int lda,
            const unsigned short* __restrict__ Bhi, const unsigned short* __restrict__ Blo, int ldb,
            int kTotal,
            float* __restrict__ partial, int* __restrict__ cnt,
            const float* __restrict__ velocity, const float* __restrict__ W_ih,
            float* __restrict__ gout_f, unsigned short* __restrict__ gout_b,
            unsigned short* __restrict__ hhi_out, unsigned short* __restrict__ hlo_out,
            int t, int mode) {
    __shared__ __align__(16) unsigned short sAh[128 * 64];
    __shared__ __align__(16) unsigned short sAl[128 * 64];
    __shared__ __align__(16) unsigned short sBh[128 * 64];
    __shared__ __align__(16) unsigned short sBl[128 * 64];
    __shared__ int sOld;

    const int tid  = threadIdx.x;
    const int lane = tid & 63;
    const int w    = tid >> 6;
    const int wr   = w >> 1;
    const int wc   = w & 1;

    // XCD-colocating decode: g&7 = XCD (round-robin dispatch heuristic)
    const int g      = blockIdx.x;
    const int xcd    = g & 7;
    const int slot   = g >> 3;
    const int n_tile = xcd * 4 + (slot >> 4);
    const int rem    = slot & 15;
    const int kc     = rem >> 1;
    const int m_tile = rem & 1;

    const int m0 = m_tile * 128;
    const int n0 = n_tile * 128;
    const int kPer  = kTotal / KSPLIT;
    const int kBase = kc * kPer;
    const int nIter = kPer / 64;

    f32x4 acc[4][4];
#pragma unroll
    for (int i = 0; i < 4; i++)
#pragma unroll
        for (int j = 0; j < 4; j++) acc[i][j] = (f32x4){0.f, 0.f, 0.f, 0.f};

    for (int it = 0; it < nIter; ++it) {
        const int k0 = kBase + it * 64;
        __syncthreads();
        stage16(Ahi, lda, m0, k0, sAh, w, lane);
        stage16(Alo, lda, m0, k0, sAl, w, lane);
        stage16(Bhi, ldb, n0, k0, sBh, w, lane);
        stage16(Blo, ldb, n0, k0, sBl, w, lane);
        __syncthreads();
#pragma unroll
        for (int ks2 = 0; ks2 < 2; ks2++) {
            bf16x8 ah[4], al[4], bh[4], bl[4];
            const unsigned int klane = (unsigned)(lane >> 4) * 16u + (unsigned)ks2 * 64u;
#pragma unroll
            for (int fm = 0; fm < 4; fm++) {
                const unsigned int row = (unsigned)(wr * 64 + fm * 16 + (lane & 15));
                const unsigned int off = (row * 128u + klane) ^ ((row & 7u) << 4);
                ah[fm] = *(const bf16x8*)((const char*)sAh + off);
                al[fm] = *(const bf16x8*)((const char*)sAl + off);
            }
#pragma unroll
            for (int fn = 0; fn < 4; fn++) {
                const unsigned int row = (unsigned)(wc * 64 + fn * 16 + (lane & 15));
                const unsigned int off = (row * 128u + klane) ^ ((row & 7u) << 4);
                bh[fn] = *(const bf16x8*)((const char*)sBh + off);
                bl[fn] = *(const bf16x8*)((const char*)sBl + off);
            }
#pragma unroll
            for (int fm = 0; fm < 4; fm++)
#pragma unroll
                for (int fn = 0; fn < 4; fn++) {
                    acc[fm][fn] = __builtin_amdgcn_mfma_f32_16x16x32_bf16(ah[fm], bh[fn], acc[fm][fn], 0, 0, 0);
                    acc[fm][fn] = __builtin_amdgcn_mfma_f32_16x16x32_bf16(ah[fm], bl[fn], acc[fm][fn], 0, 0, 0);
                    acc[fm][fn] = __builtin_amdgcn_mfma_f32_16x16x32_bf16(al[fm], bh[fn], acc[fm][fn], 0, 0, 0);
                }
        }
    }

    // write this WG's K-partial
    float* po = partial + (size_t)kc * ((size_t)kMP * kNG);
#pragma unroll
    for (int fm = 0; fm < 4; fm++)
#pragma unroll
        for (int fn = 0; fn < 4; fn++) {
            const int row0 = m0 + wr * 64 + fm * 16 + ((lane >> 4) << 2);
            const int col  = n0 + wc * 64 + fn * 16 + (lane & 15);
#pragma unroll
            for (int j = 0; j < 4; j++)
                po[(size_t)(row0 + j) * kNG + col] = acc[fm][fn][j];
        }

    // split-K semaphore
    __threadfence();
    __syncthreads();
    const int tile = m_tile * 32 + n_tile;
    if (tid == 0) sOld = atomicAdd(&cnt[tile], 1);
    __syncthreads();
    if (sOld != KSPLIT - 1) return;

    // ---- finisher: reduce 8 partials, vx + ReLU, write g / h ----
    __threadfence();
    const int tr   = tid >> 1;
    const int half = tid & 1;
    const int row  = m0 + tr;         // padded row == batch index b
    const bool live = row < kB;
    float2 vel = {0.f, 0.f};
    if (mode == 1 && live)
        vel = *(const float2*)(velocity + ((size_t)t * kB + row) * 2);

#pragma unroll 4
    for (int c = 0; c < 16; ++c) {
        const int col = n0 + half * 64 + c * 4;
        if (live) {
            float4 s = *(const float4*)(partial + (size_t)row * kNG + col);
#pragma unroll
            for (int q = 1; q < KSPLIT; ++q) {
                float4 p = *(const float4*)(partial + (size_t)q * ((size_t)kMP * kNG) + (size_t)row * kNG + col);
                s.x += p.x; s.y += p.y; s.z += p.z; s.w += p.w;
            }
            if (mode == 1) {
                const float4 w01 = *(const float4*)(W_ih + (size_t)col * 2);
                const float4 w23 = *(const float4*)(W_ih + (size_t)col * 2 + 4);
                s.x = fmaxf(0.f, s.x + vel.x * w01.x + vel.y * w01.y);
                s.y = fmaxf(0.f, s.y + vel.x * w01.z + vel.y * w01.w);
                s.z = fmaxf(0.f, s.z + vel.x * w23.x + vel.y * w23.y);
                s.w = fmaxf(0.f, s.w + vel.x * w23.z + vel.y * w23.w);
                *(float4*)(gout_f + ((size_t)t * kB + row) * kNG + col) = s;
            }
            ushort4 hh, hl;
            hh.x = f2bf(s.x); hl.x = f2bf(s.x - bf2f(hh.x));
            hh.y = f2bf(s.y); hl.y = f2bf(s.y - bf2f(hh.y));
            hh.z = f2bf(s.z); hl.z = f2bf(s.z - bf2f(hh.z));
            hh.w = f2bf(s.w); hl.w = f2bf(s.w - bf2f(hh.w));
            *(ushort4*)(hhi_out + (size_t)row * kNG + col) = hh;
            *(ushort4*)(hlo_out + (size_t)row * kNG + col) = hl;
            if (mode == 1 && gout_b) {
                ushort4 hb; hb.x = hh.x; hb.y = hh.y; hb.z = hh.z; hb.w = hh.w;
                // g bf16 copy for the decoder (hi part == bf16 round of g)
                *(ushort4*)(gout_b + ((size_t)t * kB + row) * kNG + col) = hb;
            }
        } else {
            ushort4 z; z.x = z.y = z.z = z.w = 0;
            *(ushort4*)(hhi_out + (size_t)row * kNG + col) = z;
            *(ushort4*)(hlo_out + (size_t)row * kNG + col) = z;
        }
    }
    if (tid == 0) atomicExch(&cnt[tile], 0);
}

// ---------------------------------------------------------------------------
// Decoder: logits[r][p] = sum_g G[r][g] * Wdec[p][g], single-bf16 MFMA.
// Gb (bf16 G) used if non-null, else Gf (fp32) converted during staging.
// Grid: (kNP/128, ceil(20000/128)), 256 threads.
// ---------------------------------------------------------------------------
__global__ __launch_bounds__(256, 2)
void k_dec(const float* __restrict__ Gf, const unsigned short* __restrict__ Gb,
           const unsigned short* __restrict__ Bhi, float* __restrict__ out) {
    __shared__ __align__(16) unsigned short sA[128 * 64];
    __shared__ __align__(16) unsigned short sB[128 * 64];

    const int tid  = threadIdx.x;
    const int lane = tid & 63;
    const int w    = tid >> 6;
    const int wr   = w >> 1;
    const int wc   = w & 1;
    const int m0   = blockIdx.y * 128;
    const int n0   = blockIdx.x * 128;
    const int M    = kSEQ * kB;   // 20000

    f32x4 acc[4][4];
#pragma unroll
    for (int i = 0; i < 4; i++)
#pragma unroll
        for (int j = 0; j < 4; j++) acc[i][j] = (f32x4){0.f, 0.f, 0.f, 0.f};

    const int sr   = tid >> 1;
    const int half = tid & 1;
    int arow = m0 + sr; if (arow > M - 1) arow = M - 1;

    for (int k0 = 0; k0 < kNG; k0 += 64) {
        __syncthreads();
        if (Gb) {
            // bf16 G: direct async staging with per-slot row clamp
#pragma unroll
            for (int j = 0; j < 4; ++j) {
                int s   = w * 256 + j * 64 + lane;
                int row = s >> 3;
                int c16 = s & 7;
                int csw = c16 ^ (row & 7);
                int grow = m0 + row; if (grow > M - 1) grow = M - 1;
                const char* src = (const char*)(Gb + (size_t)grow * kNG + k0) + csw * 16;
                char* dst = (char*)sA + (size_t)(w * 256 + j * 64) * 16;
                gld_lds16(src, dst);
            }
        } else {
            const float4* gA = (const float4*)(Gf + (size_t)arow * kNG + k0) + half * 8;
#pragma unroll
            for (int i = 0; i < 4; ++i) {
                float4 v0 = gA[2 * i], v1 = gA[2 * i + 1];
                uint4 u;
                u.x = (unsigned)f2bf(v0.x) | ((unsigned)f2bf(v0.y) << 16);
                u.y = (unsigned)f2bf(v0.z) | ((unsigned)f2bf(v0.w) << 16);
                u.z = (unsigned)f2bf(v1.x) | ((unsigned)f2bf(v1.y) << 16);
                u.w = (unsigned)f2bf(v1.z) | ((unsigned)f2bf(v1.w) << 16);
                int c16 = half * 4 + i;
                int off = sr * 128 + ((c16 ^ (sr & 7)) * 16);
                *(uint4*)((char*)sA + off) = u;
            }
        }
        stage16(Bhi, kNG, n0, k0, sB, w, lane);
        __syncthreads();
#pragma unroll
        for (int ks2 = 0; ks2 < 2; ks2++) {
            bf16x8 a[4], bfr[4];
            const unsigned int klane = (unsigned)(lane >> 4) * 16u + (unsigned)ks2 * 64u;
#pragma unroll
            for (int fm = 0; fm < 4; fm++) {
                const unsigned int row = (unsigned)(wr * 64 + fm * 16 + (lane & 15));
                const unsigned int off = (row * 128u + klane) ^ ((row & 7u) << 4);
                a[fm] = *(const bf16x8*)((const char*)sA + off);
            }
#pragma unroll
            for (int fn = 0; fn < 4; fn++) {
                const unsigned int row = (unsigned)(wc * 64 + fn * 16 + (lane & 15));
                const unsigned int off = (row * 128u + klane) ^ ((row & 7u) << 4);
                bfr[fn] = *(const bf16x8*)((const char*)sB + off);
            }
#pragma unroll
            for (int fm = 0; fm < 4; fm++)
#pragma unroll
                for (int fn = 0; fn < 4; fn++)
                    acc[fm][fn] = __builtin_amdgcn_mfma_f32_16x16x32_bf16(a[fm], bfr[fn], acc[fm][fn], 0, 0, 0);
        }
    }

#pragma unroll
    for (int fm = 0; fm < 4; fm++)
#pragma unroll
        for (int fn = 0; fn < 4; fn++) {
            const int row0 = m0 + wr * 64 + fm * 16 + ((lane >> 4) << 2);
            const int col  = n0 + wc * 64 + fn * 16 + (lane & 15);
#pragma unroll
            for (int j = 0; j < 4; j++) {
                const int row = row0 + j;
                if (row < M) out[(size_t)row * kNP + col] = acc[fm][fn][j];
            }
        }
}

// ---------------------------------------------------------------------------
extern "C" void kernel_launch(void* const* d_in, const int* in_sizes, int n_in,
                              void* d_out, int out_size, void* d_ws, size_t ws_size,
                              hipStream_t stream) {
    const float* velocity = (const float*)d_in[0];
    const float* init_pc  = (const float*)d_in[1];
    const float* W_enc    = (const float*)d_in[2];
    const float* W_ih     = (const float*)d_in[3];
    const float* W_hh     = (const float*)d_in[4];
    const float* W_dec    = (const float*)d_in[5];

    float* logits = (float*)d_out;                         // (100,200,512)
    float* gout   = logits + (size_t)kSEQ * kB * kNP;      // (100,200,4096)

    char* ws = (char*)d_ws;
    size_t off = 0;
    auto alloc = [&](size_t bytes) -> void* {
        void* p = ws + off;
        off += (bytes + 255) & ~(size_t)255;
        return p;
    };
    unsigned short* whh_hi  = (unsigned short*)alloc((size_t)kNG * kNG * 2);
    unsigned short* whh_lo  = (unsigned short*)alloc((size_t)kNG * kNG * 2);
    unsigned short* wdec_hi = (unsigned short*)alloc((size_t)kNP * kNG * 2);
    unsigned short* wdec_lo = (unsigned short*)alloc((size_t)kNP * kNG * 2);
    unsigned short* wenc_hi = (unsigned short*)alloc((size_t)kNG * kNP * 2);
    unsigned short* wenc_lo = (unsigned short*)alloc((size_t)kNG * kNP * 2);
    unsigned short* ip_hi   = (unsigned short*)alloc((size_t)kMP * kNP * 2);
    unsigned short* ip_lo   = (unsigned short*)alloc((size_t)kMP * kNP * 2);
    unsigned short* h_hi[2], *h_lo[2];
    h_hi[0] = (unsigned short*)alloc((size_t)kMP * kNG * 2);
    h_lo[0] = (unsigned short*)alloc((size_t)kMP * kNG * 2);
    h_hi[1] = (unsigned short*)alloc((size_t)kMP * kNG * 2);
    h_lo[1] = (unsigned short*)alloc((size_t)kMP * kNG * 2);
    float* partial = (float*)alloc((size_t)KSPLIT * kMP * kNG * 4);
    int*   cnt     = (int*)alloc(64 * 4);
    // optional bf16 copy of g for the decoder (164 MB) — only if ws allows
    unsigned short* gb = nullptr;
    if (ws_size >= off + (size_t)kSEQ * kB * kNG * 2 + 4096)
        gb = (unsigned short*)alloc((size_t)kSEQ * kB * kNG * 2);

    // zero the split-K semaphores + init_pc pad rows (h pads are written by finishers)
    hipMemsetAsync(cnt, 0, 64 * 4, stream);
    hipMemsetAsync(ip_hi + (size_t)kB * kNP, 0, (size_t)(kMP - kB) * kNP * 2, stream);
    hipMemsetAsync(ip_lo + (size_t)kB * kNP, 0, (size_t)(kMP - kB) * kNP * 2, stream);

    // --- pre-split weights / initial state ---
    int n4;
    n4 = kNG * kNG / 4;
    k_split<<<(n4 + 255) / 256, 256, 0, stream>>>(W_hh, whh_hi, whh_lo, n4);
    n4 = kNP * kNG / 4;
    k_split<<<(n4 + 255) / 256, 256, 0, stream>>>(W_dec, wdec_hi, wdec_lo, n4);
    n4 = kNG * kNP / 4;
    k_split<<<(n4 + 255) / 256, 256, 0, stream>>>(W_enc, wenc_hi, wenc_lo, n4);
    n4 = kB * kNP / 4;
    k_split<<<(n4 + 255) / 256, 256, 0, stream>>>(init_pc, ip_hi, ip_lo, n4);

    // --- encoder: h0 = init_pc @ W_enc^T ---
    k_step<<<512, 256, 0, stream>>>(ip_hi, ip_lo, kNP, wenc_hi, wenc_lo, kNP, kNP,
                                    partial, cnt, velocity, W_ih,
                                    nullptr, nullptr, h_hi[0], h_lo[0], 0, 0);

    // --- recurrent scan (fused gemm + reduce epilogue) ---
    int p = 0;
    for (int t = 0; t < kSEQ; t++) {
        k_step<<<512, 256, 0, stream>>>(h_hi[p], h_lo[p], kNG, whh_hi, whh_lo, kNG, kNG,
                                        partial, cnt, velocity, W_ih,
                                        gout, gb, h_hi[p ^ 1], h_lo[p ^ 1], t, 1);
        p ^= 1;
    }

    // --- decoder ---
    dim3 gD(kNP / 128, (kSEQ * kB + 127) / 128);   // (4, 157)
    k_dec<<<gD, 256, 0, stream>>>(gout, gb, wdec_hi, logits);
}

// Round 3
// 4365.885 us; speedup vs baseline: 4.4721x; 4.4721x over previous
//
#include <hip/hip_runtime.h>
#include <cstdint>
#include <cstddef>

// Problem constants
#define kSEQ 100
#define kB   200
#define kNP  512
#define kNG  4096
#define kMP  256     // padded M for recurrent/encoder GEMMs
#define KSPLIT 8

typedef __bf16 bf16_t;
typedef bf16_t bf16x8 __attribute__((ext_vector_type(8)));
typedef float  f32x4  __attribute__((ext_vector_type(4)));

__device__ __forceinline__ unsigned short f2bf(float f) {
    unsigned int u = __builtin_bit_cast(unsigned int, f);
    unsigned int r = (u + 0x7FFFu + ((u >> 16) & 1u)) >> 16;
    return (unsigned short)r;
}
__device__ __forceinline__ float bf2f(unsigned short b) {
    unsigned int u = ((unsigned int)b) << 16;
    return __builtin_bit_cast(float, u);
}

// ---------------------------------------------------------------------------
// Split fp32 -> (hi, lo) bf16 pair.  n4 = number of float4 groups.
// ---------------------------------------------------------------------------
__global__ __launch_bounds__(256)
void k_split(const float* __restrict__ src, unsigned short* __restrict__ hi,
             unsigned short* __restrict__ lo, int n4) {
    int i = blockIdx.x * 256 + threadIdx.x;
    if (i >= n4) return;
    float4 v = ((const float4*)src)[i];
    ushort4 h, l;
    h.x = f2bf(v.x); l.x = f2bf(v.x - bf2f(h.x));
    h.y = f2bf(v.y); l.y = f2bf(v.y - bf2f(h.y));
    h.z = f2bf(v.z); l.z = f2bf(v.z - bf2f(h.z));
    h.w = f2bf(v.w); l.w = f2bf(v.w - bf2f(h.w));
    ((ushort4*)hi)[i] = h;
    ((ushort4*)lo)[i] = l;
}

// ---------------------------------------------------------------------------
// Split-precision bf16 MFMA GEMM:  part[ks][m][n] = sum_k A[m][k]*B[n][k]
// over this block's K-chunk.  A = (Ahi+Alo), B = (Bhi+Blo); 3 products.
// Grid: (N/128, kMP/128, KSPLIT).  256 threads, 4 waves of 64x64.
// 512 blocks -> 2 blocks/CU (LDS 64KB, VGPR ~112).
// ---------------------------------------------------------------------------
__global__ __launch_bounds__(256)
void k_gemm_split(const unsigned short* __restrict__ Ahi, const unsigned short* __restrict__ Alo, int lda,
                  const unsigned short* __restrict__ Bhi, const unsigned short* __restrict__ Blo, int ldb,
                  float* __restrict__ part, int kPerChunk) {
    __shared__ __align__(16) unsigned short sAh[128 * 64];
    __shared__ __align__(16) unsigned short sAl[128 * 64];
    __shared__ __align__(16) unsigned short sBh[128 * 64];
    __shared__ __align__(16) unsigned short sBl[128 * 64];

    const int tid  = threadIdx.x;
    const int lane = tid & 63;
    const int wid  = tid >> 6;
    const int wr   = wid >> 1;   // wave row (0..1)
    const int wc   = wid & 1;    // wave col (0..1)
    const int m0   = blockIdx.y * 128;
    const int n0   = blockIdx.x * 128;
    const int kBase = blockIdx.z * kPerChunk;

    f32x4 acc[4][4];
#pragma unroll
    for (int i = 0; i < 4; i++)
#pragma unroll
        for (int j = 0; j < 4; j++) acc[i][j] = (f32x4){0.f, 0.f, 0.f, 0.f};

    const int sr = tid >> 1;          // staging row 0..127
    const int sc = (tid & 1) * 32;    // staging col offset (bf16 elems)
    const unsigned int swzrow = ((unsigned)sr & 7u) << 4;
    const unsigned int sbase  = (unsigned)sr * 128u + (unsigned)(tid & 1) * 64u;

    for (int kb = 0; kb < kPerChunk; kb += 64) {
        const int k0 = kBase + kb;
        __syncthreads();
        {
            const uint4* gAh = (const uint4*)(Ahi + (size_t)(m0 + sr) * (size_t)lda + k0 + sc);
            const uint4* gAl = (const uint4*)(Alo + (size_t)(m0 + sr) * (size_t)lda + k0 + sc);
            const uint4* gBh = (const uint4*)(Bhi + (size_t)(n0 + sr) * (size_t)ldb + k0 + sc);
            const uint4* gBl = (const uint4*)(Blo + (size_t)(n0 + sr) * (size_t)ldb + k0 + sc);
#pragma unroll
            for (int i = 0; i < 4; i++) {
                unsigned int off = (sbase + (unsigned)i * 16u) ^ swzrow;
                *(uint4*)((char*)sAh + off) = gAh[i];
                *(uint4*)((char*)sAl + off) = gAl[i];
                *(uint4*)((char*)sBh + off) = gBh[i];
                *(uint4*)((char*)sBl + off) = gBl[i];
            }
        }
        __syncthreads();
#pragma unroll
        for (int ks2 = 0; ks2 < 2; ks2++) {
            bf16x8 ah[4], al[4], bh[4], bl[4];
            const unsigned int klane = (unsigned)(lane >> 4) * 16u + (unsigned)ks2 * 64u;
#pragma unroll
            for (int fm = 0; fm < 4; fm++) {
                const unsigned int row = (unsigned)(wr * 64 + fm * 16 + (lane & 15));
                const unsigned int off = (row * 128u + klane) ^ ((row & 7u) << 4);
                ah[fm] = *(const bf16x8*)((const char*)sAh + off);
                al[fm] = *(const bf16x8*)((const char*)sAl + off);
            }
#pragma unroll
            for (int fn = 0; fn < 4; fn++) {
                const unsigned int row = (unsigned)(wc * 64 + fn * 16 + (lane & 15));
                const unsigned int off = (row * 128u + klane) ^ ((row & 7u) << 4);
                bh[fn] = *(const bf16x8*)((const char*)sBh + off);
                bl[fn] = *(const bf16x8*)((const char*)sBl + off);
            }
#pragma unroll
            for (int fm = 0; fm < 4; fm++)
#pragma unroll
                for (int fn = 0; fn < 4; fn++) {
                    acc[fm][fn] = __builtin_amdgcn_mfma_f32_16x16x32_bf16(ah[fm], bh[fn], acc[fm][fn], 0, 0, 0);
                    acc[fm][fn] = __builtin_amdgcn_mfma_f32_16x16x32_bf16(ah[fm], bl[fn], acc[fm][fn], 0, 0, 0);
                    acc[fm][fn] = __builtin_amdgcn_mfma_f32_16x16x32_bf16(al[fm], bh[fn], acc[fm][fn], 0, 0, 0);
                }
        }
    }

    float* po = part + (size_t)blockIdx.z * ((size_t)kMP * kNG);
#pragma unroll
    for (int fm = 0; fm < 4; fm++)
#pragma unroll
        for (int fn = 0; fn < 4; fn++) {
            const int row0 = m0 + wr * 64 + fm * 16 + ((lane >> 4) << 2);
            const int col  = n0 + wc * 64 + fn * 16 + (lane & 15);
#pragma unroll
            for (int j = 0; j < 4; j++)
                po[(size_t)(row0 + j) * kNG + col] = acc[fm][fn][j];
        }
}

// ---------------------------------------------------------------------------
// Reduce KSPLIT K-partials; mode 1: add velocity*W_ih^T, ReLU, store g (fp32
// + bf16 copy) and next-h (bf16 hi/lo).  mode 0 (encoder): just split h0.
// Grid: (4, kB), 256 threads, 4 g's per thread.
// ---------------------------------------------------------------------------
__global__ __launch_bounds__(256)
void k_reduce(const float* __restrict__ part,
              const float* __restrict__ velocity, const float* __restrict__ W_ih,
              float* __restrict__ gout, unsigned short* __restrict__ gb,
              unsigned short* __restrict__ hhi, unsigned short* __restrict__ hlo,
              int t, int mode) {
    const int b = blockIdx.y;
    const int g = blockIdx.x * 1024 + threadIdx.x * 4;

    float4 s = *(const float4*)(part + (size_t)b * kNG + g);
    float v0 = s.x, v1 = s.y, v2 = s.z, v3 = s.w;
#pragma unroll
    for (int ks = 1; ks < KSPLIT; ks++) {
        float4 p = *(const float4*)(part + (size_t)ks * ((size_t)kMP * kNG) + (size_t)b * kNG + g);
        v0 += p.x; v1 += p.y; v2 += p.z; v3 += p.w;
    }
    if (mode == 1) {
        const float2 vel = *(const float2*)(velocity + ((size_t)t * kB + b) * 2);
        const float4 w01 = *(const float4*)(W_ih + (size_t)g * 2);
        const float4 w23 = *(const float4*)(W_ih + (size_t)g * 2 + 4);
        v0 = fmaxf(0.f, v0 + vel.x * w01.x + vel.y * w01.y);
        v1 = fmaxf(0.f, v1 + vel.x * w01.z + vel.y * w01.w);
        v2 = fmaxf(0.f, v2 + vel.x * w23.x + vel.y * w23.y);
        v3 = fmaxf(0.f, v3 + vel.x * w23.z + vel.y * w23.w);
        float4 o; o.x = v0; o.y = v1; o.z = v2; o.w = v3;
        *(float4*)(gout + ((size_t)t * kB + b) * kNG + g) = o;
    }
    ushort4 hh, hl;
    hh.x = f2bf(v0); hl.x = f2bf(v0 - bf2f(hh.x));
    hh.y = f2bf(v1); hl.y = f2bf(v1 - bf2f(hh.y));
    hh.z = f2bf(v2); hl.z = f2bf(v2 - bf2f(hh.z));
    hh.w = f2bf(v3); hl.w = f2bf(v3 - bf2f(hh.w));
    *(ushort4*)(hhi + (size_t)b * kNG + g) = hh;
    *(ushort4*)(hlo + (size_t)b * kNG + g) = hl;
    if (mode == 1 && gb)
        *(ushort4*)(gb + ((size_t)t * kB + b) * kNG + g) = hh;
}

// ---------------------------------------------------------------------------
// Decoder: logits[r][p] = sum_g G[r][g] * Wdec[p][g], single-bf16 MFMA.
// Gb (bf16 G) used if non-null, else Gf (fp32) converted during staging.
// Flat grid 632, XCD-colocated decode: the 4 n-tiles of an m-panel land on
// the same XCD so G rows are fetched into that L2 once (not 4x from HBM).
// ---------------------------------------------------------------------------
__global__ __launch_bounds__(256)
void k_dec(const float* __restrict__ Gf, const unsigned short* __restrict__ Gb,
           const unsigned short* __restrict__ Bhi, float* __restrict__ out) {
    __shared__ __align__(16) unsigned short sA[128 * 64];
    __shared__ __align__(16) unsigned short sB[128 * 64];

    const int bid  = blockIdx.x;        // 0..631
    const int xcd  = bid & 7;
    const int idx  = bid >> 3;          // 0..78
    const int tile = xcd * 79 + idx;    // tile = m_t*4 + n_t
    if (tile >= 157 * 4) return;        // uniform early-out (before any barrier)
    const int m0 = (tile >> 2) * 128;
    const int n0 = (tile & 3) * 128;

    const int tid  = threadIdx.x;
    const int lane = tid & 63;
    const int wid  = tid >> 6;
    const int wr   = wid >> 1;
    const int wc   = wid & 1;
    const int M    = kSEQ * kB;   // 20000

    f32x4 acc[4][4];
#pragma unroll
    for (int i = 0; i < 4; i++)
#pragma unroll
        for (int j = 0; j < 4; j++) acc[i][j] = (f32x4){0.f, 0.f, 0.f, 0.f};

    const int sr   = tid >> 1;
    const int half = tid & 1;
    const int sc   = half * 32;                    // bf16-elem col offset
    const unsigned int swzrow = ((unsigned)sr & 7u) << 4;
    const unsigned int sbase  = (unsigned)sr * 128u + (unsigned)half * 64u;
    int arow = m0 + sr; if (arow > M - 1) arow = M - 1;

    for (int k0 = 0; k0 < kNG; k0 += 64) {
        __syncthreads();
        if (Gb) {
            // bf16 G: identical pattern to B-staging (measured 0 conflicts)
            const uint4* gA = (const uint4*)(Gb + (size_t)arow * kNG + k0 + sc);
#pragma unroll
            for (int i = 0; i < 4; i++) {
                unsigned int off = (sbase + (unsigned)i * 16u) ^ swzrow;
                *(uint4*)((char*)sA + off) = gA[i];
            }
        } else {
            // fp32 fallback: convert + packed b128 stores (same addresses)
            const float4* gA = (const float4*)(Gf + (size_t)arow * kNG + k0 + sc);
#pragma unroll
            for (int i = 0; i < 4; i++) {
                float4 a0 = gA[2 * i], a1 = gA[2 * i + 1];
                uint4 u;
                u.x = (unsigned)f2bf(a0.x) | ((unsigned)f2bf(a0.y) << 16);
                u.y = (unsigned)f2bf(a0.z) | ((unsigned)f2bf(a0.w) << 16);
                u.z = (unsigned)f2bf(a1.x) | ((unsigned)f2bf(a1.y) << 16);
                u.w = (unsigned)f2bf(a1.z) | ((unsigned)f2bf(a1.w) << 16);
                unsigned int off = (sbase + (unsigned)i * 16u) ^ swzrow;
                *(uint4*)((char*)sA + off) = u;
            }
        }
        {
            const uint4* gB = (const uint4*)(Bhi + (size_t)(n0 + sr) * kNG + k0 + sc);
#pragma unroll
            for (int i = 0; i < 4; i++) {
                unsigned int off = (sbase + (unsigned)i * 16u) ^ swzrow;
                *(uint4*)((char*)sB + off) = gB[i];
            }
        }
        __syncthreads();
#pragma unroll
        for (int ks2 = 0; ks2 < 2; ks2++) {
            bf16x8 a[4], bfr[4];
            const unsigned int klane = (unsigned)(lane >> 4) * 16u + (unsigned)ks2 * 64u;
#pragma unroll
            for (int fm = 0; fm < 4; fm++) {
                const unsigned int row = (unsigned)(wr * 64 + fm * 16 + (lane & 15));
                const unsigned int off = (row * 128u + klane) ^ ((row & 7u) << 4);
                a[fm] = *(const bf16x8*)((const char*)sA + off);
            }
#pragma unroll
            for (int fn = 0; fn < 4; fn++) {
                const unsigned int row = (unsigned)(wc * 64 + fn * 16 + (lane & 15));
                const unsigned int off = (row * 128u + klane) ^ ((row & 7u) << 4);
                bfr[fn] = *(const bf16x8*)((const char*)sB + off);
            }
#pragma unroll
            for (int fm = 0; fm < 4; fm++)
#pragma unroll
                for (int fn = 0; fn < 4; fn++)
                    acc[fm][fn] = __builtin_amdgcn_mfma_f32_16x16x32_bf16(a[fm], bfr[fn], acc[fm][fn], 0, 0, 0);
        }
    }

#pragma unroll
    for (int fm = 0; fm < 4; fm++)
#pragma unroll
        for (int fn = 0; fn < 4; fn++) {
            const int row0 = m0 + wr * 64 + fm * 16 + ((lane >> 4) << 2);
            const int col  = n0 + wc * 64 + fn * 16 + (lane & 15);
#pragma unroll
            for (int j = 0; j < 4; j++) {
                const int row = row0 + j;
                if (row < M) out[(size_t)row * kNP + col] = acc[fm][fn][j];
            }
        }
}

// ---------------------------------------------------------------------------
extern "C" void kernel_launch(void* const* d_in, const int* in_sizes, int n_in,
                              void* d_out, int out_size, void* d_ws, size_t ws_size,
                              hipStream_t stream) {
    const float* velocity = (const float*)d_in[0];
    const float* init_pc  = (const float*)d_in[1];
    const float* W_enc    = (const float*)d_in[2];
    const float* W_ih     = (const float*)d_in[3];
    const float* W_hh     = (const float*)d_in[4];
    const float* W_dec    = (const float*)d_in[5];

    float* logits = (float*)d_out;                         // (100,200,512)
    float* gout   = logits + (size_t)kSEQ * kB * kNP;      // (100,200,4096)

    char* ws = (char*)d_ws;
    size_t off = 0;
    auto alloc = [&](size_t bytes) -> void* {
        void* p = ws + off;
        off += (bytes + 255) & ~(size_t)255;
        return p;
    };
    unsigned short* whh_hi  = (unsigned short*)alloc((size_t)kNG * kNG * 2);
    unsigned short* whh_lo  = (unsigned short*)alloc((size_t)kNG * kNG * 2);
    unsigned short* wdec_hi = (unsigned short*)alloc((size_t)kNP * kNG * 2);
    unsigned short* wdec_lo = (unsigned short*)alloc((size_t)kNP * kNG * 2);
    unsigned short* wenc_hi = (unsigned short*)alloc((size_t)kNG * kNP * 2);
    unsigned short* wenc_lo = (unsigned short*)alloc((size_t)kNG * kNP * 2);
    unsigned short* ip_hi   = (unsigned short*)alloc((size_t)kMP * kNP * 2);
    unsigned short* ip_lo   = (unsigned short*)alloc((size_t)kMP * kNP * 2);
    unsigned short* h_hi[2], *h_lo[2];
    h_hi[0] = (unsigned short*)alloc((size_t)kMP * kNG * 2);
    h_lo[0] = (unsigned short*)alloc((size_t)kMP * kNG * 2);
    h_hi[1] = (unsigned short*)alloc((size_t)kMP * kNG * 2);
    h_lo[1] = (unsigned short*)alloc((size_t)kMP * kNG * 2);
    float* partial = (float*)alloc((size_t)KSPLIT * kMP * kNG * 4);
    // optional bf16 copy of g for the decoder (164 MB) — only if ws allows
    unsigned short* gb = nullptr;
    if (ws_size >= off + (size_t)kSEQ * kB * kNG * 2 + 4096)
        gb = (unsigned short*)alloc((size_t)kSEQ * kB * kNG * 2);

    // zero the init_pc pad rows (h pads feed discarded partial rows only)
    hipMemsetAsync(ip_hi + (size_t)kB * kNP, 0, (size_t)(kMP - kB) * kNP * 2, stream);
    hipMemsetAsync(ip_lo + (size_t)kB * kNP, 0, (size_t)(kMP - kB) * kNP * 2, stream);

    // --- pre-split weights / initial state ---
    int n4;
    n4 = kNG * kNG / 4;
    k_split<<<(n4 + 255) / 256, 256, 0, stream>>>(W_hh, whh_hi, whh_lo, n4);
    n4 = kNP * kNG / 4;
    k_split<<<(n4 + 255) / 256, 256, 0, stream>>>(W_dec, wdec_hi, wdec_lo, n4);
    n4 = kNG * kNP / 4;
    k_split<<<(n4 + 255) / 256, 256, 0, stream>>>(W_enc, wenc_hi, wenc_lo, n4);
    n4 = kB * kNP / 4;
    k_split<<<(n4 + 255) / 256, 256, 0, stream>>>(init_pc, ip_hi, ip_lo, n4);

    dim3 gG(kNG / 128, kMP / 128, KSPLIT);   // (32, 2, 8) = 512 blocks
    dim3 gR(4, kB);

    // --- encoder: h0 = init_pc @ W_enc^T ---
    k_gemm_split<<<gG, 256, 0, stream>>>(ip_hi, ip_lo, kNP, wenc_hi, wenc_lo, kNP, partial, kNP / KSPLIT);
    k_reduce<<<gR, 256, 0, stream>>>(partial, velocity, W_ih, nullptr, nullptr, h_hi[0], h_lo[0], 0, 0);

    // --- recurrent scan ---
    int p = 0;
    for (int t = 0; t < kSEQ; t++) {
        k_gemm_split<<<gG, 256, 0, stream>>>(h_hi[p], h_lo[p], kNG, whh_hi, whh_lo, kNG, partial, kNG / KSPLIT);
        k_reduce<<<gR, 256, 0, stream>>>(partial, velocity, W_ih, gout, gb, h_hi[p ^ 1], h_lo[p ^ 1], t, 1);
        p ^= 1;
    }

    // --- decoder ---
    k_dec<<<632, 256, 0, stream>>>(gout, gb, wdec_hi, logits);
}